// Round 6
// baseline (1002.831 us; speedup 1.0000x reference)
//
#include <hip/hip_runtime.h>

typedef __attribute__((ext_vector_type(8))) short short8;
typedef __attribute__((ext_vector_type(4))) float floatx4;

__device__ inline unsigned short f2bf(float f) {
  union { float f; unsigned u; } x; x.f = f;
  unsigned r = x.u + 0x7FFFu + ((x.u >> 16) & 1u);
  return (unsigned short)(r >> 16);
}
__device__ inline float bf2f(unsigned short h) {
  union { unsigned u; float f; } x; x.u = ((unsigned)h) << 16;
  return x.f;
}

// ---------------- W -> bf16 (all linear [k][c][q]) + zero BN-partial buffers ----------------
__global__ __launch_bounds__(256) void convw_kernel(const float* __restrict__ W1,
                                                    const float* __restrict__ W2,
                                                    const float* __restrict__ Wup,
                                                    unsigned short* __restrict__ W1t,
                                                    unsigned short* __restrict__ W2t,
                                                    unsigned short* __restrict__ Wupt,
                                                    float* __restrict__ parts) {
  int idx = blockIdx.x * 256 + threadIdx.x;
  const int n1 = 27 * 96 * 64;
  const int n2 = 27 * 64 * 64;
  const int n3 = 8 * 32 * 96;
  if (idx < n1) {
    int k = idx / (96 * 64);
    int r = idx % (96 * 64);
    int q = r / 64, c = r % 64;
    W1t[((size_t)k * 64 + c) * 96 + q] = f2bf(W1[idx]);
  } else if (idx < n1 + n2) {
    int j = idx - n1;
    int k = j / 4096;
    int r = j % 4096;
    int q = r / 64, c = r % 64;
    W2t[((size_t)k * 64 + c) * 64 + q] = f2bf(W2[j]);
  } else if (idx < n1 + n2 + n3) {
    int o = idx - n1 - n2;
    int k = o / 3072;
    int r = o % 3072;
    int c = r / 96, q = r % 96;
    Wupt[o] = f2bf(Wup[((size_t)k * 96 + q) * 32 + c]);
  } else if (idx < n1 + n2 + n3 + 320) {
    parts[idx - n1 - n2 - n3] = 0.f;  // upP1(32) upP2(32) c1P1(64) c1P2(64) c2P1(64) c2P2(64)
  }
}

// ---------------- Upsample via masked 8-tap MFMA (atomic BN partials) ----------------
__global__ __launch_bounds__(256) void up_mfma_kernel(const float* __restrict__ x1,
                                                      const int* __restrict__ up_src,
                                                      const int* __restrict__ up_off,
                                                      const unsigned short* __restrict__ Wupt,
                                                      float* __restrict__ up_raw,
                                                      float* __restrict__ part1,
                                                      float* __restrict__ part2,
                                                      int N) {
  constexpr int PAD = 104;
  __shared__ unsigned short Wl[8 * 32 * PAD];
  __shared__ float wsum[4][32];
  __shared__ float wsq[4][32];

  const int tid = threadIdx.x;
  const int wv = tid >> 6;
  const int lane = tid & 63;
  const int lr = lane & 15;
  const int lg = lane >> 4;

  for (int ch = tid; ch < 8 * 32 * 12; ch += 256) {
    int kc = ch / 12, j = ch % 12;
    short8 v = *(const short8*)(Wupt + (size_t)kc * 96 + j * 8);
    *(short8*)(&Wl[kc * PAD + j * 8]) = v;
  }
  __syncthreads();

  const int nTiles = (N + 63) >> 6;
  const short8 z8 = {0, 0, 0, 0, 0, 0, 0, 0};
  float cs[2] = {0.f, 0.f}, cq[2] = {0.f, 0.f};

  for (int tile = blockIdx.x; tile < nTiles; tile += gridDim.x) {
    const int base = tile * 64;
    const int r = base + wv * 16 + lr;
    int o = -100;
    const float* ptr = x1;
    if (r < N) {
      o = up_off[r];
      ptr = x1 + (size_t)up_src[r] * 96;
    }
    short8 a_all[3];
    #pragma unroll
    for (int s = 0; s < 3; ++s) {
      float4 f0 = *(const float4*)(ptr + s * 32 + lg * 8);
      float4 f1 = *(const float4*)(ptr + s * 32 + lg * 8 + 4);
      unsigned short u[8];
      u[0] = f2bf(f0.x); u[1] = f2bf(f0.y); u[2] = f2bf(f0.z); u[3] = f2bf(f0.w);
      u[4] = f2bf(f1.x); u[5] = f2bf(f1.y); u[6] = f2bf(f1.z); u[7] = f2bf(f1.w);
      a_all[s] = *(short8*)u;
    }
    if (r >= N) {
      #pragma unroll
      for (int s = 0; s < 3; ++s) a_all[s] = z8;
    }

    floatx4 acc[2];
    acc[0] = (floatx4){0.f, 0.f, 0.f, 0.f};
    acc[1] = (floatx4){0.f, 0.f, 0.f, 0.f};
    #pragma unroll
    for (int k = 0; k < 8; ++k) {
      bool sel = (o == k);
      #pragma unroll
      for (int s = 0; s < 3; ++s) {
        short8 af = sel ? a_all[s] : z8;
        #pragma unroll
        for (int ct = 0; ct < 2; ++ct) {
          short8 bf = *(const short8*)(&Wl[(k * 32 + ct * 16 + lr) * PAD + s * 32 + lg * 8]);
          acc[ct] = __builtin_amdgcn_mfma_f32_16x16x32_bf16(af, bf, acc[ct], 0, 0, 0);
        }
      }
    }
    #pragma unroll
    for (int ct = 0; ct < 2; ++ct) {
      #pragma unroll
      for (int reg = 0; reg < 4; ++reg) {
        float v = acc[ct][reg];
        int r2 = base + wv * 16 + lg * 4 + reg;
        if (r2 < N) up_raw[(size_t)r2 * 32 + ct * 16 + lr] = v;
        cs[ct] += v;
        cq[ct] += v * v;
      }
    }
  }

  #pragma unroll
  for (int ct = 0; ct < 2; ++ct) {
    float a = cs[ct], b = cq[ct];
    a += __shfl_xor(a, 16);
    a += __shfl_xor(a, 32);
    b += __shfl_xor(b, 16);
    b += __shfl_xor(b, 32);
    if (lg == 0) {
      wsum[wv][ct * 16 + lr] = a;
      wsq[wv][ct * 16 + lr] = b;
    }
  }
  __syncthreads();
  if (tid < 32) {
    float s1 = wsum[0][tid] + wsum[1][tid] + wsum[2][tid] + wsum[3][tid];
    float s2 = wsq[0][tid] + wsq[1][tid] + wsq[2][tid] + wsq[3][tid];
    atomicAdd(&part1[tid], s1);
    atomicAdd(&part2[tid], s2);
  }
}

// ---------------- Concat (folds BN-up finalize) ----------------
__global__ __launch_bounds__(256) void concat_kernel(const float* __restrict__ up_raw,
                                                     const float* __restrict__ x2,
                                                     const float* __restrict__ x3,
                                                     const float* __restrict__ part1,
                                                     const float* __restrict__ part2,
                                                     const float* __restrict__ g,
                                                     const float* __restrict__ b,
                                                     unsigned short* __restrict__ xb,
                                                     int N) {
  __shared__ float ssb[64];
  if (threadIdx.x < 32) {
    int c = threadIdx.x;
    float mean = part1[c] / (float)N;
    float var = part2[c] / (float)N - mean * mean;
    float sc = g[c] * rsqrtf(var + 1e-5f);
    ssb[c] = sc;
    ssb[32 + c] = b[c] - mean * sc;
  }
  __syncthreads();
  int total = N * 12;
  for (int idx = blockIdx.x * 256 + threadIdx.x; idx < total; idx += gridDim.x * 256) {
    int row = idx / 12, p = idx % 12;
    float v[8];
    if (p < 4) {
      const float* s = up_raw + (size_t)row * 32 + p * 8;
      int c0 = p * 8;
      #pragma unroll
      for (int j = 0; j < 8; ++j) v[j] = fmaxf(s[j] * ssb[c0 + j] + ssb[32 + c0 + j], 0.f);
    } else if (p < 8) {
      const float* s = x2 + (size_t)row * 32 + (p - 4) * 8;
      #pragma unroll
      for (int j = 0; j < 8; ++j) v[j] = s[j];
    } else {
      const float* s = x3 + (size_t)row * 32 + (p - 8) * 8;
      #pragma unroll
      for (int j = 0; j < 8; ++j) v[j] = s[j];
    }
    unsigned short o[8];
    #pragma unroll
    for (int j = 0; j < 8; ++j) o[j] = f2bf(v[j]);
    ((uint4*)xb)[idx] = *(uint4*)o;
  }
}

// ---------------- SubM conv: barrier-free, pipelined A-gather, 64-row blocks ----------------
// Block = 64 rows x 64 cols; wave wv owns rows [base+wv*16,+16) x all 64 cols (m=1).
template <int CIN, bool OUTBF>
__global__ __launch_bounds__(256, 4) void conv_kernel(const unsigned short* __restrict__ feats,
                                                      const unsigned short* __restrict__ Wt,
                                                      const int* __restrict__ nbr,
                                                      void* __restrict__ yout,
                                                      float* __restrict__ part1,
                                                      float* __restrict__ part2,
                                                      int N) {
  constexpr int KS = CIN / 32;
  const int tid = threadIdx.x;
  const int wv = tid >> 6;
  const int lane = tid & 63;
  const int lr = lane & 15;
  const int lg = lane >> 4;
  const int base = blockIdx.x * 64;
  const int r = base + wv * 16 + lr;
  const bool inb = (r < N);
  const int* nrow = nbr + (size_t)r * 27;
  const short8 z8 = {0, 0, 0, 0, 0, 0, 0, 0};

  floatx4 acc[4];
  #pragma unroll
  for (int ct = 0; ct < 4; ++ct) acc[ct] = (floatx4){0.f, 0.f, 0.f, 0.f};

  short8 Aa[KS], Ab[KS];
  int idx_cur, idx_next;

  // prologue: gather tap 0 into Aa, prefetch index for tap 1
  idx_cur = inb ? nrow[0] : -1;
  #pragma unroll
  for (int s = 0; s < KS; ++s) Aa[s] = z8;
  if (idx_cur >= 0) {
    const unsigned short* src = feats + (size_t)idx_cur * CIN + lg * 8;
    #pragma unroll
    for (int s = 0; s < KS; ++s) Aa[s] = *(const short8*)(src + s * 32);
  }
  idx_next = inb ? nrow[1] : -1;

  auto STEP = [&](int t, short8 (&Ac)[KS], short8 (&An)[KS]) {
    // prefetch index for tap t+2
    int idx_n2 = (inb && t + 2 < 27) ? nrow[t + 2] : -1;
    // issue gather for tap t+1 (lands during this tap's MFMA + next tap's B loads)
    #pragma unroll
    for (int s = 0; s < KS; ++s) An[s] = z8;
    if (idx_next >= 0) {
      const unsigned short* src = feats + (size_t)idx_next * CIN + lg * 8;
      #pragma unroll
      for (int s = 0; s < KS; ++s) An[s] = *(const short8*)(src + s * 32);
    }
    // compute tap t if any of this wave's 16 rows has a valid neighbor
    if (__any(idx_cur >= 0)) {
      short8 B[4][KS];
      const unsigned short* wsrc = Wt + ((size_t)t * 64 + lr) * CIN + lg * 8;
      #pragma unroll
      for (int ct = 0; ct < 4; ++ct)
        #pragma unroll
        for (int s = 0; s < KS; ++s)
          B[ct][s] = *(const short8*)(wsrc + ct * 16 * CIN + s * 32);
      #pragma unroll
      for (int s = 0; s < KS; ++s)
        #pragma unroll
        for (int ct = 0; ct < 4; ++ct)
          acc[ct] = __builtin_amdgcn_mfma_f32_16x16x32_bf16(Ac[s], B[ct][s], acc[ct], 0, 0, 0);
    }
    idx_cur = idx_next;
    idx_next = idx_n2;
  };

  #pragma unroll 1
  for (int t = 0; t < 26; t += 2) {
    STEP(t, Aa, Ab);
    STEP(t + 1, Ab, Aa);
  }
  STEP(26, Aa, Ab);

  // epilogue: store + atomic BN partials (no LDS, no barrier)
  float cs[4] = {0.f, 0.f, 0.f, 0.f}, cq[4] = {0.f, 0.f, 0.f, 0.f};
  #pragma unroll
  for (int ct = 0; ct < 4; ++ct) {
    #pragma unroll
    for (int reg = 0; reg < 4; ++reg) {
      float v = acc[ct][reg];
      int r2 = base + wv * 16 + lg * 4 + reg;
      int col = ct * 16 + lr;
      if (r2 < N) {
        if (OUTBF)
          ((unsigned short*)yout)[(size_t)r2 * 64 + col] = f2bf(v);
        else
          ((float*)yout)[(size_t)r2 * 64 + col] = v;
      }
      cs[ct] += v;
      cq[ct] += v * v;
    }
  }
  #pragma unroll
  for (int ct = 0; ct < 4; ++ct) {
    float a = cs[ct], b = cq[ct];
    a += __shfl_xor(a, 16);
    a += __shfl_xor(a, 32);
    b += __shfl_xor(b, 16);
    b += __shfl_xor(b, 32);
    if (lane < 16) {
      atomicAdd(&part1[ct * 16 + lr], a);
      atomicAdd(&part2[ct * 16 + lr], b);
    }
  }
}

// ---------------- Apply BN+ReLU in place on bf16 (folds bn1 finalize) ----------------
__global__ __launch_bounds__(256) void apply_bn_bf16_inplace(unsigned short* __restrict__ y,
                                                             const float* __restrict__ part1,
                                                             const float* __restrict__ part2,
                                                             const float* __restrict__ g,
                                                             const float* __restrict__ b,
                                                             int N) {
  __shared__ float ssb[128];
  if (threadIdx.x < 64) {
    int c = threadIdx.x;
    float mean = part1[c] / (float)N;
    float var = part2[c] / (float)N - mean * mean;
    float sc = g[c] * rsqrtf(var + 1e-5f);
    ssb[c] = sc;
    ssb[64 + c] = b[c] - mean * sc;
  }
  __syncthreads();
  int total = N * 8;
  for (int idx = blockIdx.x * 256 + threadIdx.x; idx < total; idx += gridDim.x * 256) {
    int c0 = (idx & 7) * 8;
    uint4 d = ((uint4*)y)[idx];
    unsigned short* u = (unsigned short*)&d;
    #pragma unroll
    for (int j = 0; j < 8; ++j) {
      float f = bf2f(u[j]);
      f = fmaxf(f * ssb[c0 + j] + ssb[64 + c0 + j], 0.f);
      u[j] = f2bf(f);
    }
    ((uint4*)y)[idx] = d;
  }
}

// ---------------- Apply BN+ReLU in place, fp32 (folds bn2 finalize) ----------------
__global__ __launch_bounds__(256) void apply_bn_inplace(float* __restrict__ y,
                                                        const float* __restrict__ part1,
                                                        const float* __restrict__ part2,
                                                        const float* __restrict__ g,
                                                        const float* __restrict__ b,
                                                        int N) {
  __shared__ float ssb[128];
  if (threadIdx.x < 64) {
    int c = threadIdx.x;
    float mean = part1[c] / (float)N;
    float var = part2[c] / (float)N - mean * mean;
    float sc = g[c] * rsqrtf(var + 1e-5f);
    ssb[c] = sc;
    ssb[64 + c] = b[c] - mean * sc;
  }
  __syncthreads();
  int total = N * 16;
  for (int idx = blockIdx.x * 256 + threadIdx.x; idx < total; idx += gridDim.x * 256) {
    int c0 = (idx & 15) * 4;
    float4 d = ((float4*)y)[idx];
    d.x = fmaxf(d.x * ssb[c0 + 0] + ssb[64 + c0 + 0], 0.f);
    d.y = fmaxf(d.y * ssb[c0 + 1] + ssb[64 + c0 + 1], 0.f);
    d.z = fmaxf(d.z * ssb[c0 + 2] + ssb[64 + c0 + 2], 0.f);
    d.w = fmaxf(d.w * ssb[c0 + 3] + ssb[64 + c0 + 3], 0.f);
    ((float4*)y)[idx] = d;
  }
}

extern "C" void kernel_launch(void* const* d_in, const int* in_sizes, int n_in,
                              void* d_out, int out_size, void* d_ws, size_t ws_size,
                              hipStream_t stream) {
  const float* x1 = (const float*)d_in[0];
  const float* x2 = (const float*)d_in[1];
  const float* x3 = (const float*)d_in[2];
  const float* Wup = (const float*)d_in[3];
  const float* gup = (const float*)d_in[4];
  const float* bup = (const float*)d_in[5];
  const float* W1 = (const float*)d_in[6];
  const float* g1 = (const float*)d_in[7];
  const float* b1 = (const float*)d_in[8];
  const float* W2 = (const float*)d_in[9];
  const float* g2 = (const float*)d_in[10];
  const float* b2 = (const float*)d_in[11];
  const int* up_src = (const int*)d_in[12];
  const int* up_off = (const int*)d_in[13];
  const int* nbr = (const int*)d_in[14];

  const int N = in_sizes[12];
  const int NB = (N + 63) / 64;

  char* ws = (char*)d_ws;
  size_t off = 0;
  auto alloc = [&](size_t bytes) -> void* {
    void* p = ws + off;
    off = (off + bytes + 255) & ~(size_t)255;
    return p;
  };

  unsigned short* xb   = (unsigned short*)alloc((size_t)N * 96 * 2);
  unsigned short* y1b  = (unsigned short*)alloc((size_t)N * 64 * 2);
  float* up_raw        = (float*)alloc((size_t)N * 32 * 4);
  unsigned short* W1t  = (unsigned short*)alloc((size_t)27 * 64 * 96 * 2);
  unsigned short* W2t  = (unsigned short*)alloc((size_t)27 * 64 * 64 * 2);
  unsigned short* Wupt = (unsigned short*)alloc((size_t)8 * 32 * 96 * 2);
  float* parts         = (float*)alloc(320 * 4);
  (void)ws_size;

  float* upP1 = parts;
  float* upP2 = parts + 32;
  float* c1P1 = parts + 64;
  float* c1P2 = parts + 128;
  float* c2P1 = parts + 192;
  float* c2P2 = parts + 256;

  float* out = (float*)d_out;

  // 1. W -> bf16 + zero BN-partial buffers
  convw_kernel<<<1178, 256, 0, stream>>>(W1, W2, Wup, W1t, W2t, Wupt, parts);
  // 2. upsample (MFMA, masked 8-tap, atomic partials)
  up_mfma_kernel<<<1024, 256, 0, stream>>>(x1, up_src, up_off, Wupt, up_raw, upP1, upP2, N);
  // 3. concat -> bf16 (folds BN-up)
  concat_kernel<<<2048, 256, 0, stream>>>(up_raw, x2, x3, upP1, upP2, gup, bup, xb, N);
  // 4. conv1 (bf16 out, atomic partials)
  conv_kernel<96, true><<<NB, 256, 0, stream>>>(xb, W1t, nbr, y1b, c1P1, c1P2, N);
  // 5. apply BN1 in place on bf16 (folds bn1)
  apply_bn_bf16_inplace<<<2048, 256, 0, stream>>>(y1b, c1P1, c1P2, g1, b1, N);
  // 6. conv2 (fp32 out into d_out, atomic partials)
  conv_kernel<64, false><<<NB, 256, 0, stream>>>(y1b, W2t, nbr, out, c2P1, c2P2, N);
  // 7. apply BN2 in place (folds bn2)
  apply_bn_inplace<<<2048, 256, 0, stream>>>(out, c2P1, c2P2, g2, b2, N);
}

// Round 7
// 974.107 us; speedup vs baseline: 1.0295x; 1.0295x over previous
//
#include <hip/hip_runtime.h>

typedef __attribute__((ext_vector_type(8))) short short8;
typedef __attribute__((ext_vector_type(4))) float floatx4;

__device__ inline unsigned short f2bf(float f) {
  union { float f; unsigned u; } x; x.f = f;
  unsigned r = x.u + 0x7FFFu + ((x.u >> 16) & 1u);
  return (unsigned short)(r >> 16);
}
__device__ inline float bf2f(unsigned short h) {
  union { unsigned u; float f; } x; x.u = ((unsigned)h) << 16;
  return x.f;
}

// ---------------- W -> bf16 (all linear [k][c][q]) + zero BN-partial buffers ----------------
__global__ __launch_bounds__(256) void convw_kernel(const float* __restrict__ W1,
                                                    const float* __restrict__ W2,
                                                    const float* __restrict__ Wup,
                                                    unsigned short* __restrict__ W1t,
                                                    unsigned short* __restrict__ W2t,
                                                    unsigned short* __restrict__ Wupt,
                                                    float* __restrict__ parts) {
  int idx = blockIdx.x * 256 + threadIdx.x;
  const int n1 = 27 * 96 * 64;
  const int n2 = 27 * 64 * 64;
  const int n3 = 8 * 32 * 96;
  if (idx < n1) {
    int k = idx / (96 * 64);
    int r = idx % (96 * 64);
    int q = r / 64, c = r % 64;
    W1t[((size_t)k * 64 + c) * 96 + q] = f2bf(W1[idx]);
  } else if (idx < n1 + n2) {
    int j = idx - n1;
    int k = j / 4096;
    int r = j % 4096;
    int q = r / 64, c = r % 64;
    W2t[((size_t)k * 64 + c) * 64 + q] = f2bf(W2[j]);
  } else if (idx < n1 + n2 + n3) {
    int o = idx - n1 - n2;
    int k = o / 3072;
    int r = o % 3072;
    int c = r / 96, q = r % 96;
    Wupt[o] = f2bf(Wup[((size_t)k * 96 + q) * 32 + c]);
  } else if (idx < n1 + n2 + n3 + 320) {
    parts[idx - n1 - n2 - n3] = 0.f;  // upP1(32) upP2(32) c1P1(64) c1P2(64) c2P1(64) c2P2(64)
  }
}

// ---------------- Upsample via masked 8-tap MFMA (atomic BN partials) ----------------
__global__ __launch_bounds__(256) void up_mfma_kernel(const float* __restrict__ x1,
                                                      const int* __restrict__ up_src,
                                                      const int* __restrict__ up_off,
                                                      const unsigned short* __restrict__ Wupt,
                                                      float* __restrict__ up_raw,
                                                      float* __restrict__ part1,
                                                      float* __restrict__ part2,
                                                      int N) {
  constexpr int PAD = 104;
  __shared__ unsigned short Wl[8 * 32 * PAD];
  __shared__ float wsum[4][32];
  __shared__ float wsq[4][32];

  const int tid = threadIdx.x;
  const int wv = tid >> 6;
  const int lane = tid & 63;
  const int lr = lane & 15;
  const int lg = lane >> 4;

  for (int ch = tid; ch < 8 * 32 * 12; ch += 256) {
    int kc = ch / 12, j = ch % 12;
    short8 v = *(const short8*)(Wupt + (size_t)kc * 96 + j * 8);
    *(short8*)(&Wl[kc * PAD + j * 8]) = v;
  }
  __syncthreads();

  const int nTiles = (N + 63) >> 6;
  const short8 z8 = {0, 0, 0, 0, 0, 0, 0, 0};
  float cs[2] = {0.f, 0.f}, cq[2] = {0.f, 0.f};

  for (int tile = blockIdx.x; tile < nTiles; tile += gridDim.x) {
    const int base = tile * 64;
    const int r = base + wv * 16 + lr;
    int o = -100;
    const float* ptr = x1;
    if (r < N) {
      o = up_off[r];
      ptr = x1 + (size_t)up_src[r] * 96;
    }
    short8 a_all[3];
    #pragma unroll
    for (int s = 0; s < 3; ++s) {
      float4 f0 = *(const float4*)(ptr + s * 32 + lg * 8);
      float4 f1 = *(const float4*)(ptr + s * 32 + lg * 8 + 4);
      unsigned short u[8];
      u[0] = f2bf(f0.x); u[1] = f2bf(f0.y); u[2] = f2bf(f0.z); u[3] = f2bf(f0.w);
      u[4] = f2bf(f1.x); u[5] = f2bf(f1.y); u[6] = f2bf(f1.z); u[7] = f2bf(f1.w);
      a_all[s] = *(short8*)u;
    }
    if (r >= N) {
      #pragma unroll
      for (int s = 0; s < 3; ++s) a_all[s] = z8;
    }

    floatx4 acc[2];
    acc[0] = (floatx4){0.f, 0.f, 0.f, 0.f};
    acc[1] = (floatx4){0.f, 0.f, 0.f, 0.f};
    #pragma unroll
    for (int k = 0; k < 8; ++k) {
      bool sel = (o == k);
      #pragma unroll
      for (int s = 0; s < 3; ++s) {
        short8 af = sel ? a_all[s] : z8;
        #pragma unroll
        for (int ct = 0; ct < 2; ++ct) {
          short8 bf = *(const short8*)(&Wl[(k * 32 + ct * 16 + lr) * PAD + s * 32 + lg * 8]);
          acc[ct] = __builtin_amdgcn_mfma_f32_16x16x32_bf16(af, bf, acc[ct], 0, 0, 0);
        }
      }
    }
    #pragma unroll
    for (int ct = 0; ct < 2; ++ct) {
      #pragma unroll
      for (int reg = 0; reg < 4; ++reg) {
        float v = acc[ct][reg];
        int r2 = base + wv * 16 + lg * 4 + reg;
        if (r2 < N) up_raw[(size_t)r2 * 32 + ct * 16 + lr] = v;
        cs[ct] += v;
        cq[ct] += v * v;
      }
    }
  }

  #pragma unroll
  for (int ct = 0; ct < 2; ++ct) {
    float a = cs[ct], b = cq[ct];
    a += __shfl_xor(a, 16);
    a += __shfl_xor(a, 32);
    b += __shfl_xor(b, 16);
    b += __shfl_xor(b, 32);
    if (lg == 0) {
      wsum[wv][ct * 16 + lr] = a;
      wsq[wv][ct * 16 + lr] = b;
    }
  }
  __syncthreads();
  if (tid < 32) {
    float s1 = wsum[0][tid] + wsum[1][tid] + wsum[2][tid] + wsum[3][tid];
    float s2 = wsq[0][tid] + wsq[1][tid] + wsq[2][tid] + wsq[3][tid];
    atomicAdd(&part1[tid], s1);
    atomicAdd(&part2[tid], s2);
  }
}

// ---------------- Concat (folds BN-up finalize) ----------------
__global__ __launch_bounds__(256) void concat_kernel(const float* __restrict__ up_raw,
                                                     const float* __restrict__ x2,
                                                     const float* __restrict__ x3,
                                                     const float* __restrict__ part1,
                                                     const float* __restrict__ part2,
                                                     const float* __restrict__ g,
                                                     const float* __restrict__ b,
                                                     unsigned short* __restrict__ xb,
                                                     int N) {
  __shared__ float ssb[64];
  if (threadIdx.x < 32) {
    int c = threadIdx.x;
    float mean = part1[c] / (float)N;
    float var = part2[c] / (float)N - mean * mean;
    float sc = g[c] * rsqrtf(var + 1e-5f);
    ssb[c] = sc;
    ssb[32 + c] = b[c] - mean * sc;
  }
  __syncthreads();
  int total = N * 12;
  for (int idx = blockIdx.x * 256 + threadIdx.x; idx < total; idx += gridDim.x * 256) {
    int row = idx / 12, p = idx % 12;
    float v[8];
    if (p < 4) {
      const float* s = up_raw + (size_t)row * 32 + p * 8;
      int c0 = p * 8;
      #pragma unroll
      for (int j = 0; j < 8; ++j) v[j] = fmaxf(s[j] * ssb[c0 + j] + ssb[32 + c0 + j], 0.f);
    } else if (p < 8) {
      const float* s = x2 + (size_t)row * 32 + (p - 4) * 8;
      #pragma unroll
      for (int j = 0; j < 8; ++j) v[j] = s[j];
    } else {
      const float* s = x3 + (size_t)row * 32 + (p - 8) * 8;
      #pragma unroll
      for (int j = 0; j < 8; ++j) v[j] = s[j];
    }
    unsigned short o[8];
    #pragma unroll
    for (int j = 0; j < 8; ++j) o[j] = f2bf(v[j]);
    ((uint4*)xb)[idx] = *(uint4*)o;
  }
}

// ---------------- SubM conv: barrier-free, depth-2 rotating A pipeline ----------------
// Block = 64 rows; wave wv owns rows [base+wv*16,+16) x all 64 cols (ct=0..3).
// A pipeline: 3 named buffers; stage T gathers tap T+2 (issued FIRST), computes tap T.

#define GATHER(I, A)                                                           \
  {                                                                            \
    _Pragma("unroll")                                                          \
    for (int s = 0; s < KS; ++s) A[s] = z8;                                    \
    if ((I) >= 0) {                                                            \
      const unsigned short* _gsrc = feats + (size_t)(I) * CIN + lg * 8;        \
      _Pragma("unroll")                                                        \
      for (int s = 0; s < KS; ++s) A[s] = *(const short8*)(_gsrc + s * 32);    \
    }                                                                          \
  }

#define STAGE(T, AX, AY, AZ, I0, I1, I2)                                       \
  {                                                                            \
    if ((T) + 2 < 27) GATHER(I2, AZ);                                          \
    int _ni = ((T) + 3 < 27 && inb) ? nrow[(T) + 3] : -1;                      \
    if (__any((I0) >= 0)) {                                                    \
      const unsigned short* _wsrc =                                            \
          Wt + ((size_t)(T) * 64 + lr) * CIN + lg * 8;                         \
      _Pragma("unroll")                                                        \
      for (int ct = 0; ct < 4; ++ct) {                                         \
        short8 _bb[KS];                                                        \
        _Pragma("unroll")                                                      \
        for (int s = 0; s < KS; ++s)                                           \
          _bb[s] = *(const short8*)(_wsrc + ct * 16 * CIN + s * 32);           \
        _Pragma("unroll")                                                      \
        for (int s = 0; s < KS; ++s)                                           \
          acc[ct] = __builtin_amdgcn_mfma_f32_16x16x32_bf16(AX[s], _bb[s],     \
                                                            acc[ct], 0, 0, 0); \
      }                                                                        \
    }                                                                          \
    (I0) = _ni;                                                                \
  }

template <int CIN, bool OUTBF>
__global__ __launch_bounds__(256) void conv_kernel(const unsigned short* __restrict__ feats,
                                                   const unsigned short* __restrict__ Wt,
                                                   const int* __restrict__ nbr,
                                                   void* __restrict__ yout,
                                                   float* __restrict__ part1,
                                                   float* __restrict__ part2,
                                                   int N) {
  constexpr int KS = CIN / 32;
  const int tid = threadIdx.x;
  const int wv = tid >> 6;
  const int lane = tid & 63;
  const int lr = lane & 15;
  const int lg = lane >> 4;

  // XCD-aware bijective block remap (T1)
  int nwg = gridDim.x, orig = blockIdx.x;
  int qq = nwg >> 3, rr = nwg & 7, xcd = orig & 7, jj = orig >> 3;
  int bid = (xcd < rr ? xcd * (qq + 1) : rr * (qq + 1) + (xcd - rr) * qq) + jj;
  const int base = bid * 64;

  const int r = base + wv * 16 + lr;
  const bool inb = (r < N);
  const int* nrow = nbr + (size_t)r * 27;
  const short8 z8 = {0, 0, 0, 0, 0, 0, 0, 0};

  floatx4 acc[4];
  #pragma unroll
  for (int ct = 0; ct < 4; ++ct) acc[ct] = (floatx4){0.f, 0.f, 0.f, 0.f};

  int i0 = inb ? nrow[0] : -1;
  int i1 = inb ? nrow[1] : -1;
  int i2 = inb ? nrow[2] : -1;
  short8 A0[KS], A1[KS], A2[KS];
  GATHER(i0, A0);
  GATHER(i1, A1);

  #pragma unroll 1
  for (int t = 0; t < 27; t += 3) {
    STAGE(t,     A0, A1, A2, i0, i1, i2);
    STAGE(t + 1, A1, A2, A0, i1, i2, i0);
    STAGE(t + 2, A2, A0, A1, i2, i0, i1);
  }

  // epilogue: store + atomic BN partials (no LDS, no barrier)
  float cs[4] = {0.f, 0.f, 0.f, 0.f}, cq[4] = {0.f, 0.f, 0.f, 0.f};
  #pragma unroll
  for (int ct = 0; ct < 4; ++ct) {
    #pragma unroll
    for (int reg = 0; reg < 4; ++reg) {
      float v = acc[ct][reg];
      int r2 = base + wv * 16 + lg * 4 + reg;
      int col = ct * 16 + lr;
      if (r2 < N) {
        if (OUTBF)
          ((unsigned short*)yout)[(size_t)r2 * 64 + col] = f2bf(v);
        else
          ((float*)yout)[(size_t)r2 * 64 + col] = v;
      }
      cs[ct] += v;
      cq[ct] += v * v;
    }
  }
  #pragma unroll
  for (int ct = 0; ct < 4; ++ct) {
    float a = cs[ct], b = cq[ct];
    a += __shfl_xor(a, 16);
    a += __shfl_xor(a, 32);
    b += __shfl_xor(b, 16);
    b += __shfl_xor(b, 32);
    if (lane < 16) {
      atomicAdd(&part1[ct * 16 + lr], a);
      atomicAdd(&part2[ct * 16 + lr], b);
    }
  }
}

#undef STAGE
#undef GATHER

// ---------------- Apply BN+ReLU in place on bf16 (folds bn1 finalize) ----------------
__global__ __launch_bounds__(256) void apply_bn_bf16_inplace(unsigned short* __restrict__ y,
                                                             const float* __restrict__ part1,
                                                             const float* __restrict__ part2,
                                                             const float* __restrict__ g,
                                                             const float* __restrict__ b,
                                                             int N) {
  __shared__ float ssb[128];
  if (threadIdx.x < 64) {
    int c = threadIdx.x;
    float mean = part1[c] / (float)N;
    float var = part2[c] / (float)N - mean * mean;
    float sc = g[c] * rsqrtf(var + 1e-5f);
    ssb[c] = sc;
    ssb[64 + c] = b[c] - mean * sc;
  }
  __syncthreads();
  int total = N * 8;
  for (int idx = blockIdx.x * 256 + threadIdx.x; idx < total; idx += gridDim.x * 256) {
    int c0 = (idx & 7) * 8;
    uint4 d = ((uint4*)y)[idx];
    unsigned short* u = (unsigned short*)&d;
    #pragma unroll
    for (int j = 0; j < 8; ++j) {
      float f = bf2f(u[j]);
      f = fmaxf(f * ssb[c0 + j] + ssb[64 + c0 + j], 0.f);
      u[j] = f2bf(f);
    }
    ((uint4*)y)[idx] = d;
  }
}

// ---------------- Apply BN+ReLU in place, fp32 (folds bn2 finalize) ----------------
__global__ __launch_bounds__(256) void apply_bn_inplace(float* __restrict__ y,
                                                        const float* __restrict__ part1,
                                                        const float* __restrict__ part2,
                                                        const float* __restrict__ g,
                                                        const float* __restrict__ b,
                                                        int N) {
  __shared__ float ssb[128];
  if (threadIdx.x < 64) {
    int c = threadIdx.x;
    float mean = part1[c] / (float)N;
    float var = part2[c] / (float)N - mean * mean;
    float sc = g[c] * rsqrtf(var + 1e-5f);
    ssb[c] = sc;
    ssb[64 + c] = b[c] - mean * sc;
  }
  __syncthreads();
  int total = N * 16;
  for (int idx = blockIdx.x * 256 + threadIdx.x; idx < total; idx += gridDim.x * 256) {
    int c0 = (idx & 15) * 4;
    float4 d = ((float4*)y)[idx];
    d.x = fmaxf(d.x * ssb[c0 + 0] + ssb[64 + c0 + 0], 0.f);
    d.y = fmaxf(d.y * ssb[c0 + 1] + ssb[64 + c0 + 1], 0.f);
    d.z = fmaxf(d.z * ssb[c0 + 2] + ssb[64 + c0 + 2], 0.f);
    d.w = fmaxf(d.w * ssb[c0 + 3] + ssb[64 + c0 + 3], 0.f);
    ((float4*)y)[idx] = d;
  }
}

extern "C" void kernel_launch(void* const* d_in, const int* in_sizes, int n_in,
                              void* d_out, int out_size, void* d_ws, size_t ws_size,
                              hipStream_t stream) {
  const float* x1 = (const float*)d_in[0];
  const float* x2 = (const float*)d_in[1];
  const float* x3 = (const float*)d_in[2];
  const float* Wup = (const float*)d_in[3];
  const float* gup = (const float*)d_in[4];
  const float* bup = (const float*)d_in[5];
  const float* W1 = (const float*)d_in[6];
  const float* g1 = (const float*)d_in[7];
  const float* b1 = (const float*)d_in[8];
  const float* W2 = (const float*)d_in[9];
  const float* g2 = (const float*)d_in[10];
  const float* b2 = (const float*)d_in[11];
  const int* up_src = (const int*)d_in[12];
  const int* up_off = (const int*)d_in[13];
  const int* nbr = (const int*)d_in[14];

  const int N = in_sizes[12];
  const int NB = (N + 63) / 64;

  char* ws = (char*)d_ws;
  size_t off = 0;
  auto alloc = [&](size_t bytes) -> void* {
    void* p = ws + off;
    off = (off + bytes + 255) & ~(size_t)255;
    return p;
  };

  unsigned short* xb   = (unsigned short*)alloc((size_t)N * 96 * 2);
  unsigned short* y1b  = (unsigned short*)alloc((size_t)N * 64 * 2);
  float* up_raw        = (float*)alloc((size_t)N * 32 * 4);
  unsigned short* W1t  = (unsigned short*)alloc((size_t)27 * 64 * 96 * 2);
  unsigned short* W2t  = (unsigned short*)alloc((size_t)27 * 64 * 64 * 2);
  unsigned short* Wupt = (unsigned short*)alloc((size_t)8 * 32 * 96 * 2);
  float* parts         = (float*)alloc(320 * 4);
  (void)ws_size;

  float* upP1 = parts;
  float* upP2 = parts + 32;
  float* c1P1 = parts + 64;
  float* c1P2 = parts + 128;
  float* c2P1 = parts + 192;
  float* c2P2 = parts + 256;

  float* out = (float*)d_out;

  // 1. W -> bf16 + zero BN-partial buffers
  convw_kernel<<<1178, 256, 0, stream>>>(W1, W2, Wup, W1t, W2t, Wupt, parts);
  // 2. upsample (MFMA, masked 8-tap, atomic partials)
  up_mfma_kernel<<<1024, 256, 0, stream>>>(x1, up_src, up_off, Wupt, up_raw, upP1, upP2, N);
  // 3. concat -> bf16 (folds BN-up)
  concat_kernel<<<2048, 256, 0, stream>>>(up_raw, x2, x3, upP1, upP2, gup, bup, xb, N);
  // 4. conv1 (bf16 out, atomic partials)
  conv_kernel<96, true><<<NB, 256, 0, stream>>>(xb, W1t, nbr, y1b, c1P1, c1P2, N);
  // 5. apply BN1 in place on bf16 (folds bn1)
  apply_bn_bf16_inplace<<<2048, 256, 0, stream>>>(y1b, c1P1, c1P2, g1, b1, N);
  // 6. conv2 (fp32 out into d_out, atomic partials)
  conv_kernel<64, false><<<NB, 256, 0, stream>>>(y1b, W2t, nbr, out, c2P1, c2P2, N);
  // 7. apply BN2 in place (folds bn2)
  apply_bn_inplace<<<2048, 256, 0, stream>>>(out, c2P1, c2P2, g2, b2, N);
}